// Round 3
// baseline (4452.620 us; speedup 1.0000x reference)
//
#include <hip/hip_runtime.h>

// ---------------------------------------------------------------------------
// FC-LSTM encoder/decoder on MI355X.
// All GEMMs in bf16 MFMA (16x16x32), fp32 accumulate. c-state fp32, h bf16.
// LSTM layer kernel: 128 wgs x 4 waves; wave w = gate w; wg owns 16 h-cols.
// Weights converted fp32->bf16 once per call into d_ws (re-poisoned each call).
// ---------------------------------------------------------------------------

typedef __bf16 v8bf __attribute__((ext_vector_type(8)));
typedef float  v4f  __attribute__((ext_vector_type(4)));
typedef unsigned short u16;
typedef const unsigned int __attribute__((address_space(1)))* gas1p;
typedef unsigned int __attribute__((address_space(3)))* las3p;

#define MFMA(a, b, c) __builtin_amdgcn_mfma_f32_16x16x32_bf16(a, b, c, 0, 0, 0)

static __device__ __forceinline__ u16 f2bf(float x) {
    unsigned u = __float_as_uint(x);
    return (u16)((u + 0x7fffu + ((u >> 16) & 1u)) >> 16);  // RNE
}

static __device__ __forceinline__ void gl_lds16(const void* g, void* l) {
    // async global->LDS, 16B/lane; LDS dest = wave-uniform base + lane*16
    __builtin_amdgcn_global_load_lds((gas1p)g, (las3p)l, 16, 0, 0);
}

// fp32 -> bf16 elementwise, 8 elems/thread
__global__ __launch_bounds__(256) void k_cvt(const float* __restrict__ s,
                                             u16* __restrict__ d, long n) {
    long i = (long)blockIdx.x * blockDim.x + threadIdx.x;
    long stride = (long)gridDim.x * blockDim.x;
    for (; i * 8 < n; i += stride) {
        const float4* p = (const float4*)(s + i * 8);
        float4 a = p[0], b = p[1];
        uint4 o;
        o.x = (unsigned)f2bf(a.x) | ((unsigned)f2bf(a.y) << 16);
        o.y = (unsigned)f2bf(a.z) | ((unsigned)f2bf(a.w) << 16);
        o.z = (unsigned)f2bf(b.x) | ((unsigned)f2bf(b.y) << 16);
        o.w = (unsigned)f2bf(b.z) | ((unsigned)f2bf(b.w) << 16);
        *(uint4*)(d + i * 8) = o;
    }
}

// ---------------------------------------------------------------------------
// Fused LSTM layer: gates = x@wih^T + h@whh^T + b ; cell update ; h,c out.
// x,h: [64,2048] bf16. wih,whh: [8192,2048] bf16 (row-major [N,K]).
// grid 128 (16 cols each), block 256 (wave w = gate w).
// LDS: 2 x (A[64][64] + B[64][64]) bf16 = 32KB, XOR-swizzled rows.
// ---------------------------------------------------------------------------
__global__ __launch_bounds__(256) void k_lstm(
    const u16* __restrict__ x, const u16* __restrict__ wih,
    const u16* __restrict__ h, const u16* __restrict__ whh,
    const float* __restrict__ bias, float* __restrict__ c,
    u16* __restrict__ hout) {
    __shared__ char lds[32768];
    const int tid = threadIdx.x;
    const int w = tid >> 6;
    const int lane = tid & 63;
    const int n0 = blockIdx.x << 4;

    // staging addressing (pre-swizzled global source, linear LDS dest)
    const int srow = lane >> 3;                       // row-in-segment 0..7
    const int kx = ((lane & 7) ^ srow) << 3;          // swizzle: k-elem offset
    const size_t ar0 = (size_t)((w << 4) + srow) * 2048 + kx;
    const size_t ar1 = ar0 + (size_t)8 * 2048;
    const size_t wr0 = (size_t)(w * 2048 + n0 + srow) * 2048 + kx;
    const size_t wr1 = wr0 + (size_t)8 * 2048;

    // compute-side addressing
    const int l15 = lane & 15;
    const int lg = lane >> 4;
    const int swz = (lane & 7) << 4;
    const int in0 = (lg << 4) ^ swz;
    const int in1 = (64 + (lg << 4)) ^ swz;
    const int bR = ((w << 4) + l15) << 7;             // B LDS row byte offset
    const int aR0 = l15 << 7;                         // A m=0 row byte offset

    v4f acc0 = {0.f, 0.f, 0.f, 0.f}, acc1 = acc0, acc2 = acc0, acc3 = acc0;

    auto stage = [&](int buf, int ch) {
        const u16 *s, *ws_;
        int k0;
        if (ch < 32) { s = x; ws_ = wih; k0 = ch << 6; }
        else         { s = h; ws_ = whh; k0 = (ch - 32) << 6; }
        char* base = lds + (buf << 14);
        gl_lds16(s + ar0 + k0, base + (w << 11));
        gl_lds16(s + ar1 + k0, base + (w << 11) + 1024);
        gl_lds16(ws_ + wr0 + k0, base + 8192 + (w << 11));
        gl_lds16(ws_ + wr1 + k0, base + 8192 + (w << 11) + 1024);
    };
    auto compute = [&](int buf) {
        char* base = lds + (buf << 14);
        char* bb = base + 8192;
#pragma unroll
        for (int ks = 0; ks < 2; ++ks) {
            const int inn = ks ? in1 : in0;
            v8bf bfr = *(const v8bf*)(bb + bR + inn);
            v8bf a0 = *(const v8bf*)(base + aR0 + inn);
            v8bf a1 = *(const v8bf*)(base + aR0 + 2048 + inn);
            v8bf a2 = *(const v8bf*)(base + aR0 + 4096 + inn);
            v8bf a3 = *(const v8bf*)(base + aR0 + 6144 + inn);
            acc0 = MFMA(a0, bfr, acc0);
            acc1 = MFMA(a1, bfr, acc1);
            acc2 = MFMA(a2, bfr, acc2);
            acc3 = MFMA(a3, bfr, acc3);
        }
    };

    stage(0, 0);
    for (int ch = 0; ch < 64; ++ch) {
        __syncthreads();                 // stage(ch) complete (vmcnt drain)
        if (ch < 63) stage((ch + 1) & 1, ch + 1);
        compute(ch & 1);
    }
    __syncthreads();

    // epilogue: gates -> LDS [4][64][17] fp32, then cell update
    const float bv = bias[w * 2048 + n0 + l15];
    float* gl = (float*)lds;
    const int gb = w << 6;
#pragma unroll
    for (int j = 0; j < 4; ++j) gl[(gb + 0  + (lg << 2) + j) * 17 + l15] = acc0[j] + bv;
#pragma unroll
    for (int j = 0; j < 4; ++j) gl[(gb + 16 + (lg << 2) + j) * 17 + l15] = acc1[j] + bv;
#pragma unroll
    for (int j = 0; j < 4; ++j) gl[(gb + 32 + (lg << 2) + j) * 17 + l15] = acc2[j] + bv;
#pragma unroll
    for (int j = 0; j < 4; ++j) gl[(gb + 48 + (lg << 2) + j) * 17 + l15] = acc3[j] + bv;
    __syncthreads();

#pragma unroll
    for (int r = 0; r < 4; ++r) {
        int idx = tid + (r << 8);
        int b = idx >> 4, col = idx & 15;
        float gi = gl[(0   + b) * 17 + col];
        float gf = gl[(64  + b) * 17 + col];
        float gg = gl[(128 + b) * 17 + col];
        float go = gl[(192 + b) * 17 + col];
        size_t o = ((size_t)b << 11) + n0 + col;
        float si = 1.f / (1.f + __expf(-gi));
        float sf = 1.f / (1.f + __expf(-gf));
        float so = 1.f / (1.f + __expf(-go));
        float c2 = sf * c[o] + si * tanhf(gg);
        c[o] = c2;
        hout[o] = f2bf(so * tanhf(c2));
    }
}

// ---------------------------------------------------------------------------
// Generic C = epi(A@W^T + b). A [M,K] bf16, W [N,K] bf16.
// grid (N/64, M/64), block 256. EPI: 0 relu->bf16, 1 sigmoid->f32.
// ---------------------------------------------------------------------------
template <int EPI>
__global__ __launch_bounds__(256) void k_gemm(
    const u16* __restrict__ A, int lda, const u16* __restrict__ W, int ldw,
    const float* __restrict__ bias, void* __restrict__ outp, int ldo, int K) {
    __shared__ char lds[32768];
    const int tid = threadIdx.x;
    const int w = tid >> 6;
    const int lane = tid & 63;
    const int n0 = blockIdx.x << 6;
    const int m0 = blockIdx.y << 6;

    const int srow = lane >> 3;
    const int kx = ((lane & 7) ^ srow) << 3;
    const size_t ar0 = (size_t)(m0 + (w << 4) + srow) * lda + kx;
    const size_t ar1 = ar0 + (size_t)8 * lda;
    const size_t wr0 = (size_t)(n0 + (w << 4) + srow) * ldw + kx;
    const size_t wr1 = wr0 + (size_t)8 * ldw;

    const int l15 = lane & 15;
    const int lg = lane >> 4;
    const int swz = (lane & 7) << 4;
    const int in0 = (lg << 4) ^ swz;
    const int in1 = (64 + (lg << 4)) ^ swz;
    const int bR = ((w << 4) + l15) << 7;
    const int aR0 = l15 << 7;

    v4f acc0 = {0.f, 0.f, 0.f, 0.f}, acc1 = acc0, acc2 = acc0, acc3 = acc0;
    const int nch = K >> 6;

    auto stage = [&](int buf, int ch) {
        int k0 = ch << 6;
        char* base = lds + (buf << 14);
        gl_lds16(A + ar0 + k0, base + (w << 11));
        gl_lds16(A + ar1 + k0, base + (w << 11) + 1024);
        gl_lds16(W + wr0 + k0, base + 8192 + (w << 11));
        gl_lds16(W + wr1 + k0, base + 8192 + (w << 11) + 1024);
    };
    auto compute = [&](int buf) {
        char* base = lds + (buf << 14);
        char* bb = base + 8192;
#pragma unroll
        for (int ks = 0; ks < 2; ++ks) {
            const int inn = ks ? in1 : in0;
            v8bf bfr = *(const v8bf*)(bb + bR + inn);
            v8bf a0 = *(const v8bf*)(base + aR0 + inn);
            v8bf a1 = *(const v8bf*)(base + aR0 + 2048 + inn);
            v8bf a2 = *(const v8bf*)(base + aR0 + 4096 + inn);
            v8bf a3 = *(const v8bf*)(base + aR0 + 6144 + inn);
            acc0 = MFMA(a0, bfr, acc0);
            acc1 = MFMA(a1, bfr, acc1);
            acc2 = MFMA(a2, bfr, acc2);
            acc3 = MFMA(a3, bfr, acc3);
        }
    };

    stage(0, 0);
    for (int ch = 0; ch < nch; ++ch) {
        __syncthreads();
        if (ch + 1 < nch) stage((ch + 1) & 1, ch + 1);
        compute(ch & 1);
    }

    const int colg = n0 + (w << 4) + l15;
    const float bv = bias[colg];
#pragma unroll
    for (int m = 0; m < 4; ++m) {
        v4f a = m == 0 ? acc0 : m == 1 ? acc1 : m == 2 ? acc2 : acc3;
#pragma unroll
        for (int j = 0; j < 4; ++j) {
            int row = m0 + (m << 4) + (lg << 2) + j;
            float v = a[j] + bv;
            if (EPI == 0)
                ((u16*)outp)[(size_t)row * ldo + colg] = f2bf(fmaxf(v, 0.f));
            else
                ((float*)outp)[(size_t)row * ldo + colg] = 1.f / (1.f + __expf(-v));
        }
    }
}

// ---------------------------------------------------------------------------
extern "C" void kernel_launch(void* const* d_in, const int* in_sizes, int n_in,
                              void* d_out, int out_size, void* d_ws, size_t ws_size,
                              hipStream_t stream) {
    const float* xin = (const float*)d_in[0];
    const float* we1 = (const float*)d_in[1];
    const float* be1 = (const float*)d_in[2];
    const float* we2 = (const float*)d_in[3];
    const float* be2 = (const float*)d_in[4];
    const float* ewih = (const float*)d_in[5];
    const float* ewhh = (const float*)d_in[6];
    const float* eb = (const float*)d_in[7];
    const float* dwih = (const float*)d_in[8];
    const float* dwhh = (const float*)d_in[9];
    const float* db = (const float*)d_in[10];
    const float* wd1 = (const float*)d_in[11];
    const float* bd1 = (const float*)d_in[12];
    const float* wd2 = (const float*)d_in[13];
    const float* bd2 = (const float*)d_in[14];
    float* out = (float*)d_out;

    char* ws = (char*)d_ws;
    size_t off = 0;
    auto alloc = [&](size_t b) {
        char* p = ws + off;
        off += (b + 255) & ~(size_t)255;
        return p;
    };

    const size_t WL = (size_t)8192 * 2048;  // elems per LSTM weight matrix
    u16* b_ewih = (u16*)alloc(3 * WL * 2);
    u16* b_ewhh = (u16*)alloc(3 * WL * 2);
    u16* b_dwih = (u16*)alloc(3 * WL * 2);
    u16* b_dwhh = (u16*)alloc(3 * WL * 2);
    u16* b_we1 = (u16*)alloc((size_t)1024 * 4096 * 2);
    u16* b_we2 = (u16*)alloc((size_t)2048 * 1024 * 2);
    u16* b_wd1 = (u16*)alloc((size_t)1024 * 2048 * 2);
    u16* b_wd2 = (u16*)alloc((size_t)4096 * 1024 * 2);
    u16* xbf  = (u16*)alloc((size_t)1024 * 4096 * 2);
    u16* fc1o = (u16*)alloc((size_t)1024 * 1024 * 2);
    u16* xf   = (u16*)alloc((size_t)1024 * 2048 * 2);
    u16* dfc1 = (u16*)alloc((size_t)64 * 1024 * 2);

    // contiguous zero-init block: enc_h[3][2], dec_h[3][2] (bf16), zin,
    // enc_c[3], dec_c[3] (fp32)
    const size_t HB = (size_t)64 * 2048;          // elems per state matrix
    char* zblk = alloc(6553600);
    u16* ench_ = (u16*)zblk;
    u16* dech_ = (u16*)(zblk + 1572864);
    u16* zin = (u16*)(zblk + 2 * 1572864);
    float* ecc = (float*)(zblk + 2 * 1572864 + 262144);
    float* dcc = (float*)(zblk + 2 * 1572864 + 262144 + 1572864);
    auto ench = [&](int l, int p) { return ench_ + (size_t)(l * 2 + p) * HB; };
    auto dech = [&](int l, int p) { return dech_ + (size_t)(l * 2 + p) * HB; };

    hipMemsetAsync(zblk, 0, 6553600, stream);

    auto cvt = [&](const float* s, u16* d, size_t n) {
        int blocks = (int)((n / 8 + 255) / 256);
        if (blocks > 4096) blocks = 4096;
        k_cvt<<<blocks, 256, 0, stream>>>(s, d, (long)n);
    };
    cvt(xin, xbf, (size_t)1024 * 4096);
    cvt(we1, b_we1, (size_t)1024 * 4096);
    cvt(we2, b_we2, (size_t)2048 * 1024);
    cvt(ewih, b_ewih, 3 * WL);
    cvt(ewhh, b_ewhh, 3 * WL);
    cvt(dwih, b_dwih, 3 * WL);
    cvt(dwhh, b_dwhh, 3 * WL);
    cvt(wd1, b_wd1, (size_t)1024 * 2048);
    cvt(wd2, b_wd2, (size_t)4096 * 1024);

    // encoder FC1/FC2 batched over all 16 timesteps (M = 1024)
    k_gemm<0><<<dim3(16, 16), 256, 0, stream>>>(xbf, 4096, b_we1, 4096, be1,
                                                fc1o, 1024, 4096);
    k_gemm<0><<<dim3(32, 16), 256, 0, stream>>>(fc1o, 1024, b_we2, 1024, be2,
                                                xf, 2048, 1024);

    // encoder: 16 steps x 3 LSTM layers (h ping-pong by step parity)
    for (int t = 0; t < 16; ++t) {
        int p = t & 1;
        k_lstm<<<128, 256, 0, stream>>>(xf + (size_t)t * HB, b_ewih, ench(0, p),
                                        b_ewhh, eb, ecc, ench(0, p ^ 1));
        k_lstm<<<128, 256, 0, stream>>>(ench(0, p ^ 1), b_ewih + WL, ench(1, p),
                                        b_ewhh + WL, eb + 8192, ecc + HB,
                                        ench(1, p ^ 1));
        k_lstm<<<128, 256, 0, stream>>>(ench(1, p ^ 1), b_ewih + 2 * WL, ench(2, p),
                                        b_ewhh + 2 * WL, eb + 16384, ecc + 2 * HB,
                                        ench(2, p ^ 1));
    }
    // final enc h3 lands in ench(2, 0) after t=15 (p=1 writes parity 0)

    // decoder: 16 steps x (3 LSTM + FC1 relu + FC2 sigmoid -> d_out)
    for (int d = 0; d < 16; ++d) {
        int q = d & 1;
        const u16* xi = (d == 0) ? zin : dech(2, q);
        const u16* h1 = (d == 0) ? ench(2, 0) : dech(0, q);
        k_lstm<<<128, 256, 0, stream>>>(xi, b_dwih, h1, b_dwhh, db, dcc,
                                        dech(0, q ^ 1));
        k_lstm<<<128, 256, 0, stream>>>(dech(0, q ^ 1), b_dwih + WL, dech(1, q),
                                        b_dwhh + WL, db + 8192, dcc + HB,
                                        dech(1, q ^ 1));
        k_lstm<<<128, 256, 0, stream>>>(dech(1, q ^ 1), b_dwih + 2 * WL, dech(2, q),
                                        b_dwhh + 2 * WL, db + 16384, dcc + 2 * HB,
                                        dech(2, q ^ 1));
        k_gemm<0><<<dim3(16, 1), 256, 0, stream>>>(dech(2, q ^ 1), 2048, b_wd1,
                                                   2048, bd1, dfc1, 1024, 2048);
        k_gemm<1><<<dim3(64, 1), 256, 0, stream>>>(dfc1, 1024, b_wd2, 1024, bd2,
                                                   out + (size_t)d * 64 * 4096,
                                                   4096, 1024);
    }
    (void)in_sizes; (void)n_in; (void)out_size; (void)ws_size;
}